// Round 1
// baseline (433.416 us; speedup 1.0000x reference)
//
#include <hip/hip_runtime.h>

// ---------------------------------------------------------------------------
// 2-layer GraphSAGE (mean agg) fused pipeline, fp32, MI355X.
//
//   1. k_zero       : zero degree counters / cursors
//   2. k_hist       : deg[tgt]++ per edge (int atomics)
//   3. k_scan_part / k_scan_top / k_scan_add : exclusive prefix sum -> rowstart
//   4. k_fill       : bucket src indices into CSR (colsrc)
//   5. k_layer1     : per-node gather-mean over x + fused GEMM(64->64) + lrelu -> h
//   6. k_layer2     : per-node gather-mean over h + fused GEMM(64->32) + lrelu -> out
//
// CSR build avoids ~205M fp32 atomicAdds (only ~3.2M int atomics instead).
// Node-centric aggregation: 16 threads/node, each owns 4 cols (float4).
// ---------------------------------------------------------------------------

#define NTH 256

__global__ void k_zero(int* __restrict__ p, int n) {
    int i = blockIdx.x * blockDim.x + threadIdx.x;
    int stride = gridDim.x * blockDim.x;
    for (; i < n; i += stride) p[i] = 0;
}

__global__ void k_hist(const int* __restrict__ tgt, int E, int* __restrict__ cnt) {
    int i = blockIdx.x * blockDim.x + threadIdx.x;
    int stride = gridDim.x * blockDim.x;
    for (; i < E; i += stride) atomicAdd(&cnt[tgt[i]], 1);
}

// block-local exclusive scan of cnt -> rowstart, block totals -> partials
__global__ void k_scan_part(const int* __restrict__ cnt, int N,
                            int* __restrict__ rowstart, int* __restrict__ partials) {
    __shared__ int s[NTH];
    const int tid = threadIdx.x;
    const int i = blockIdx.x * NTH + tid;
    const int v = (i < N) ? cnt[i] : 0;
    s[tid] = v;
    __syncthreads();
    for (int off = 1; off < NTH; off <<= 1) {
        int t = (tid >= off) ? s[tid - off] : 0;
        __syncthreads();
        s[tid] += t;
        __syncthreads();
    }
    if (i < N) rowstart[i] = s[tid] - v;           // exclusive
    if (tid == NTH - 1) partials[blockIdx.x] = s[tid];
}

// single-block exclusive scan of partials (B <= 512)
__global__ void k_scan_top(int* __restrict__ partials, int B) {
    __shared__ int s[512];
    const int tid = threadIdx.x;
    const int v = (tid < B) ? partials[tid] : 0;
    s[tid] = v;
    __syncthreads();
    for (int off = 1; off < 512; off <<= 1) {
        int t = (tid >= off) ? s[tid - off] : 0;
        __syncthreads();
        s[tid] += t;
        __syncthreads();
    }
    if (tid < B) partials[tid] = s[tid] - v;       // exclusive
}

__global__ void k_scan_add(int* __restrict__ rowstart, const int* __restrict__ partials, int N) {
    const int i = blockIdx.x * blockDim.x + threadIdx.x;
    if (i < N) rowstart[i] += partials[blockIdx.x];
}

__global__ void k_fill(const int* __restrict__ src, const int* __restrict__ tgt, int E,
                       const int* __restrict__ rowstart, int* __restrict__ cursor,
                       int* __restrict__ colsrc) {
    int i = blockIdx.x * blockDim.x + threadIdx.x;
    int stride = gridDim.x * blockDim.x;
    for (; i < E; i += stride) {
        const int t = tgt[i];
        const int p = atomicAdd(&cursor[t], 1);
        colsrc[rowstart[t] + p] = src[i];
    }
}

// Layer 1: agg = mean_{s in N(v)} x[s]; h[v] = lrelu(agg@Wl + b + x[v]@Wr)
// 16 nodes/block, 16 threads/node, 4 cols/thread.
__global__ __launch_bounds__(256) void k_layer1(
    const float* __restrict__ x, const int* __restrict__ rowstart,
    const int* __restrict__ cnt, const int* __restrict__ colsrc,
    const float* __restrict__ Wl, const float* __restrict__ bias,
    const float* __restrict__ Wr, float* __restrict__ h, int N) {
    __shared__ float sWl[64 * 64];
    __shared__ float sWr[64 * 64];
    __shared__ float sb[64];
    __shared__ float sAgg[16][68];   // +4 pad: groups hit distinct banks
    __shared__ float sX[16][68];

    const int tid = threadIdx.x;
    for (int i = tid; i < 1024; i += 256) {
        ((float4*)sWl)[i] = ((const float4*)Wl)[i];
        ((float4*)sWr)[i] = ((const float4*)Wr)[i];
    }
    if (tid < 64) sb[tid] = bias[tid];

    const int g = tid >> 4;           // node slot in block
    const int t = tid & 15;           // lane in node group
    const int node = blockIdx.x * 16 + g;
    const int c0 = t * 4;

    float4 acc = make_float4(0.f, 0.f, 0.f, 0.f);
    int rs = 0, deg = 0;
    if (node < N) { rs = rowstart[node]; deg = cnt[node]; }

    int e = 0;
    for (; e + 1 < deg; e += 2) {     // unroll-2 for load overlap
        const int s0 = colsrc[rs + e];
        const int s1 = colsrc[rs + e + 1];
        const float4 v0 = *(const float4*)(x + (size_t)s0 * 64 + c0);
        const float4 v1 = *(const float4*)(x + (size_t)s1 * 64 + c0);
        acc.x += v0.x + v1.x; acc.y += v0.y + v1.y;
        acc.z += v0.z + v1.z; acc.w += v0.w + v1.w;
    }
    if (e < deg) {
        const int s0 = colsrc[rs + e];
        const float4 v0 = *(const float4*)(x + (size_t)s0 * 64 + c0);
        acc.x += v0.x; acc.y += v0.y; acc.z += v0.z; acc.w += v0.w;
    }

    if (node < N) {
        const float inv = 1.0f / (float)(deg > 0 ? deg : 1);
        acc.x *= inv; acc.y *= inv; acc.z *= inv; acc.w *= inv;
        *(float4*)&sAgg[g][c0] = acc;
        *(float4*)&sX[g][c0] = *(const float4*)(x + (size_t)node * 64 + c0);
    }
    __syncthreads();

    if (node < N) {
        float o0 = sb[c0], o1 = sb[c0 + 1], o2 = sb[c0 + 2], o3 = sb[c0 + 3];
#pragma unroll 8
        for (int k = 0; k < 64; ++k) {
            const float a = sAgg[g][k];
            const float xv = sX[g][k];
            const float* wl = &sWl[k * 64 + c0];
            const float* wr = &sWr[k * 64 + c0];
            o0 += a * wl[0] + xv * wr[0];
            o1 += a * wl[1] + xv * wr[1];
            o2 += a * wl[2] + xv * wr[2];
            o3 += a * wl[3] + xv * wr[3];
        }
        float4 o;
        o.x = o0 > 0.f ? o0 : 0.01f * o0;
        o.y = o1 > 0.f ? o1 : 0.01f * o1;
        o.z = o2 > 0.f ? o2 : 0.01f * o2;
        o.w = o3 > 0.f ? o3 : 0.01f * o3;
        *(float4*)(h + (size_t)node * 64 + c0) = o;
    }
}

// Layer 2: same structure, 64 -> 32 outputs, 2 cols/thread on output side.
__global__ __launch_bounds__(256) void k_layer2(
    const float* __restrict__ h, const int* __restrict__ rowstart,
    const int* __restrict__ cnt, const int* __restrict__ colsrc,
    const float* __restrict__ Wl, const float* __restrict__ bias,
    const float* __restrict__ Wr, float* __restrict__ out, int N) {
    __shared__ float sWl[64 * 32];
    __shared__ float sWr[64 * 32];
    __shared__ float sb[32];
    __shared__ float sAgg[16][68];
    __shared__ float sH[16][68];

    const int tid = threadIdx.x;
    for (int i = tid; i < 512; i += 256) {
        ((float4*)sWl)[i] = ((const float4*)Wl)[i];
        ((float4*)sWr)[i] = ((const float4*)Wr)[i];
    }
    if (tid < 32) sb[tid] = bias[tid];

    const int g = tid >> 4;
    const int t = tid & 15;
    const int node = blockIdx.x * 16 + g;
    const int c0 = t * 4;

    float4 acc = make_float4(0.f, 0.f, 0.f, 0.f);
    int rs = 0, deg = 0;
    if (node < N) { rs = rowstart[node]; deg = cnt[node]; }

    int e = 0;
    for (; e + 1 < deg; e += 2) {
        const int s0 = colsrc[rs + e];
        const int s1 = colsrc[rs + e + 1];
        const float4 v0 = *(const float4*)(h + (size_t)s0 * 64 + c0);
        const float4 v1 = *(const float4*)(h + (size_t)s1 * 64 + c0);
        acc.x += v0.x + v1.x; acc.y += v0.y + v1.y;
        acc.z += v0.z + v1.z; acc.w += v0.w + v1.w;
    }
    if (e < deg) {
        const int s0 = colsrc[rs + e];
        const float4 v0 = *(const float4*)(h + (size_t)s0 * 64 + c0);
        acc.x += v0.x; acc.y += v0.y; acc.z += v0.z; acc.w += v0.w;
    }

    if (node < N) {
        const float inv = 1.0f / (float)(deg > 0 ? deg : 1);
        acc.x *= inv; acc.y *= inv; acc.z *= inv; acc.w *= inv;
        *(float4*)&sAgg[g][c0] = acc;
        *(float4*)&sH[g][c0] = *(const float4*)(h + (size_t)node * 64 + c0);
    }
    __syncthreads();

    if (node < N) {
        const int c = 2 * t;
        float o0 = sb[c], o1 = sb[c + 1];
#pragma unroll 8
        for (int k = 0; k < 64; ++k) {
            const float a = sAgg[g][k];
            const float hv = sH[g][k];
            o0 += a * sWl[k * 32 + c]     + hv * sWr[k * 32 + c];
            o1 += a * sWl[k * 32 + c + 1] + hv * sWr[k * 32 + c + 1];
        }
        float2 o;
        o.x = o0 > 0.f ? o0 : 0.01f * o0;
        o.y = o1 > 0.f ? o1 : 0.01f * o1;
        *(float2*)(out + (size_t)node * 32 + c) = o;
    }
}

static inline size_t align256(size_t v) { return (v + 255) & ~(size_t)255; }

extern "C" void kernel_launch(void* const* d_in, const int* in_sizes, int n_in,
                              void* d_out, int out_size, void* d_ws, size_t ws_size,
                              hipStream_t stream) {
    const float* x   = (const float*)d_in[0];
    const int* edge  = (const int*)d_in[1];   // [2,E] int32 (JAX x64 off)
    const float* W1l = (const float*)d_in[2];
    const float* b1  = (const float*)d_in[3];
    const float* W1r = (const float*)d_in[4];
    const float* W2l = (const float*)d_in[5];
    const float* b2  = (const float*)d_in[6];
    const float* W2r = (const float*)d_in[7];
    float* out = (float*)d_out;

    const int N = in_sizes[0] / 64;
    const int E = in_sizes[1] / 2;
    const int* src = edge;
    const int* tgt = edge + E;

    // workspace layout: [degcnt N][cursor N][partials 512] | [rowstart N][colsrc E][h N*64]
    char* ws = (char*)d_ws;
    int* degcnt = (int*)ws;       ws += align256((size_t)N * 4);
    int* cursor = (int*)ws;       ws += align256((size_t)N * 4);
    int* partials = (int*)ws;     ws += align256(512 * 4);
    int* rowstart = (int*)ws;     ws += align256((size_t)N * 4);
    int* colsrc = (int*)ws;       ws += align256((size_t)E * 4);
    float* h = (float*)ws;        // N*64 floats

    const int nzero = (int)(((char*)rowstart - (char*)degcnt) / 4);
    k_zero<<<512, 256, 0, stream>>>(degcnt, nzero);

    k_hist<<<2048, 256, 0, stream>>>(tgt, E, degcnt);

    const int B = (N + NTH - 1) / NTH;                 // 391 for N=100000
    k_scan_part<<<B, NTH, 0, stream>>>(degcnt, N, rowstart, partials);
    k_scan_top<<<1, 512, 0, stream>>>(partials, B);
    k_scan_add<<<B, NTH, 0, stream>>>(rowstart, partials, N);

    k_fill<<<2048, 256, 0, stream>>>(src, tgt, E, rowstart, cursor, colsrc);

    const int nb = (N + 15) / 16;                      // 6250
    k_layer1<<<nb, 256, 0, stream>>>(x, rowstart, degcnt, colsrc, W1l, b1, W1r, h, N);
    k_layer2<<<nb, 256, 0, stream>>>(h, rowstart, degcnt, colsrc, W2l, b2, W2r, out, N);
}